// Round 2
// baseline (193.946 us; speedup 1.0000x reference)
//
#include <hip/hip_runtime.h>

// Problem: B=4, C=19, H=1024, W=1024, N=500000
// out = mean_n [ log(sum_j exp(p_j)) - p_label ],  p = softmax(predict[b,:,r,c])
//
// NOTE: harness ABI passes ALL integer inputs as int32 (reference int64
// loc_* arrive as int32 on device). Reading them as long long caused the
// round-1 GPU memory fault.

#define CCH 19
#define BLOCK 256

__global__ __launch_bounds__(BLOCK) void partial_loss_gather(
    const float* __restrict__ predict,
    const int* __restrict__ target,
    const int* __restrict__ loc_b,
    const int* __restrict__ loc_row,
    const int* __restrict__ loc_col,
    float* __restrict__ partial,
    int n)
{
    int i = blockIdx.x * blockDim.x + threadIdx.x;
    float nll = 0.0f;
    if (i < n) {
        int b = loc_b[i];
        int r = loc_row[i];
        int c = loc_col[i];
        int pos = (r << 10) + c;                         // H=W=1024
        const float* base = predict + ((size_t)(b * CCH) << 20) + (size_t)pos;
        int label = target[((size_t)b << 20) + (size_t)pos];

        // 19 independent strided loads -> max MLP (compiler batches them)
        float x[CCH];
        #pragma unroll
        for (int j = 0; j < CCH; ++j) x[j] = base[(size_t)j << 20];

        // softmax over channels
        float m = x[0];
        #pragma unroll
        for (int j = 1; j < CCH; ++j) m = fmaxf(m, x[j]);

        float s = 0.0f;
        float e_label = 0.0f;
        #pragma unroll
        for (int j = 0; j < CCH; ++j) {
            float e = __expf(x[j] - m);
            s += e;
            // compile-time j vs runtime label -> v_cndmask, NOT a register-array
            // runtime index (which would spill to scratch, rule #20)
            if (j == label) e_label = e;
            x[j] = e;
        }
        float inv = 1.0f / s;

        // second log-softmax at the label: log(sum exp(p_j)) - p_label
        // p_j in (0,1] so no max-subtraction needed (sum <= 19*e, no overflow)
        float s2 = 0.0f;
        #pragma unroll
        for (int j = 0; j < CCH; ++j) s2 += __expf(x[j] * inv);

        float p_label = e_label * inv;
        nll = __logf(s2) - p_label;
    }

    // block tree reduction (deterministic)
    __shared__ float red[BLOCK];
    red[threadIdx.x] = nll;
    __syncthreads();
    #pragma unroll
    for (int off = BLOCK / 2; off > 0; off >>= 1) {
        if (threadIdx.x < off) red[threadIdx.x] += red[threadIdx.x + off];
        __syncthreads();
    }
    if (threadIdx.x == 0) partial[blockIdx.x] = red[0];
}

__global__ __launch_bounds__(BLOCK) void partial_loss_finalize(
    const float* __restrict__ partial,
    int nparts,
    float* __restrict__ out,
    float inv_n)
{
    __shared__ double red[BLOCK];
    double acc = 0.0;
    for (int i = threadIdx.x; i < nparts; i += BLOCK) acc += (double)partial[i];
    red[threadIdx.x] = acc;
    __syncthreads();
    #pragma unroll
    for (int off = BLOCK / 2; off > 0; off >>= 1) {
        if (threadIdx.x < off) red[threadIdx.x] += red[threadIdx.x + off];
        __syncthreads();
    }
    if (threadIdx.x == 0) out[0] = (float)(red[0] * (double)inv_n);
}

extern "C" void kernel_launch(void* const* d_in, const int* in_sizes, int n_in,
                              void* d_out, int out_size, void* d_ws, size_t ws_size,
                              hipStream_t stream)
{
    const float* predict = (const float*)d_in[0];
    const int*   target  = (const int*)d_in[1];
    const int*   loc_b   = (const int*)d_in[2];
    const int*   loc_row = (const int*)d_in[3];
    const int*   loc_col = (const int*)d_in[4];
    float* out = (float*)d_out;
    float* partial = (float*)d_ws;   // needs nblocks*4 B = ~7.8 KB of ws

    int n = in_sizes[2];                         // N = 500000
    int nblocks = (n + BLOCK - 1) / BLOCK;       // 1954

    partial_loss_gather<<<nblocks, BLOCK, 0, stream>>>(
        predict, target, loc_b, loc_row, loc_col, partial, n);
    partial_loss_finalize<<<1, BLOCK, 0, stream>>>(
        partial, nblocks, out, 1.0f / (float)n);
}

// Round 3
// 87.752 us; speedup vs baseline: 2.2102x; 2.2102x over previous
//
#include <hip/hip_runtime.h>

// Problem: B=4, C=19, H=1024, W=1024, N=500000
// out = mean_n [ log(sum_j exp(p_j)) - p_label ],  p = softmax(predict[b,:,r,c])
//
// Round-3 structure: random-gather of 64B lines from 304 MB (615 MB fetch,
// 2.8 TB/s random) is replaced by (A) a fully-coalesced streaming pass that
// computes nll for ALL 4M positions into a 16 MB table in d_ws, then (B) a
// random 4B gather from the L3-resident table. Falls back to the direct
// gather path if ws_size is too small.
//
// NOTE: harness ABI passes ALL integer inputs as int32.

#define CCH 19
#define BLOCK 256
#define POS_BITS 20               // H*W = 1<<20
#define TOTAL_POS (4 << POS_BITS) // B * H * W = 4M

__device__ __forceinline__ float nll_from_channels(const float* __restrict__ base,
                                                   int label, size_t ch_stride)
{
    float x[CCH];
    #pragma unroll
    for (int j = 0; j < CCH; ++j) x[j] = base[(size_t)j * ch_stride];

    float m = x[0];
    #pragma unroll
    for (int j = 1; j < CCH; ++j) m = fmaxf(m, x[j]);

    float s = 0.0f, e_label = 0.0f;
    #pragma unroll
    for (int j = 0; j < CCH; ++j) {
        float e = __expf(x[j] - m);
        s += e;
        if (j == label) e_label = e;   // compile-time j vs runtime label -> cndmask
        x[j] = e;
    }
    float inv = 1.0f / s;

    float s2 = 0.0f;
    #pragma unroll
    for (int j = 0; j < CCH; ++j) s2 += __expf(x[j] * inv);

    return __logf(s2) - e_label * inv;
}

// ---- Path 1 kernel A: streamed nll table over all positions ----
__global__ __launch_bounds__(BLOCK) void nll_table_kernel(
    const float* __restrict__ predict,
    const int* __restrict__ target,
    float* __restrict__ table)
{
    int i = blockIdx.x * blockDim.x + threadIdx.x;   // i = b*HW + pos, coalesced
    if (i >= TOTAL_POS) return;
    int b = i >> POS_BITS;
    int pos = i & ((1 << POS_BITS) - 1);
    const float* base = predict + (((size_t)b * CCH) << POS_BITS) + (size_t)pos;
    table[i] = nll_from_channels(base, target[i], (size_t)1 << POS_BITS);
}

// ---- Path 1 kernel B: random 4B gather from 16MB table + block reduce ----
__global__ __launch_bounds__(BLOCK) void table_gather_kernel(
    const float* __restrict__ table,
    const int* __restrict__ loc_b,
    const int* __restrict__ loc_row,
    const int* __restrict__ loc_col,
    float* __restrict__ partial,
    int n)
{
    int i = blockIdx.x * blockDim.x + threadIdx.x;
    float nll = 0.0f;
    if (i < n) {
        int idx = (loc_b[i] << POS_BITS) + (loc_row[i] << 10) + loc_col[i];
        nll = table[idx];
    }
    __shared__ float red[BLOCK];
    red[threadIdx.x] = nll;
    __syncthreads();
    #pragma unroll
    for (int off = BLOCK / 2; off > 0; off >>= 1) {
        if (threadIdx.x < off) red[threadIdx.x] += red[threadIdx.x + off];
        __syncthreads();
    }
    if (threadIdx.x == 0) partial[blockIdx.x] = red[0];
}

// ---- Path 2 (fallback): direct random gather (round-2 kernel) ----
__global__ __launch_bounds__(BLOCK) void partial_loss_gather(
    const float* __restrict__ predict,
    const int* __restrict__ target,
    const int* __restrict__ loc_b,
    const int* __restrict__ loc_row,
    const int* __restrict__ loc_col,
    float* __restrict__ partial,
    int n)
{
    int i = blockIdx.x * blockDim.x + threadIdx.x;
    float nll = 0.0f;
    if (i < n) {
        int b = loc_b[i];
        int pos = (loc_row[i] << 10) + loc_col[i];
        const float* base = predict + (((size_t)b * CCH) << POS_BITS) + (size_t)pos;
        int label = target[((size_t)b << POS_BITS) + (size_t)pos];
        nll = nll_from_channels(base, label, (size_t)1 << POS_BITS);
    }
    __shared__ float red[BLOCK];
    red[threadIdx.x] = nll;
    __syncthreads();
    #pragma unroll
    for (int off = BLOCK / 2; off > 0; off >>= 1) {
        if (threadIdx.x < off) red[threadIdx.x] += red[threadIdx.x + off];
        __syncthreads();
    }
    if (threadIdx.x == 0) partial[blockIdx.x] = red[0];
}

__global__ __launch_bounds__(BLOCK) void partial_loss_finalize(
    const float* __restrict__ partial,
    int nparts,
    float* __restrict__ out,
    float inv_n)
{
    __shared__ double red[BLOCK];
    double acc = 0.0;
    for (int i = threadIdx.x; i < nparts; i += BLOCK) acc += (double)partial[i];
    red[threadIdx.x] = acc;
    __syncthreads();
    #pragma unroll
    for (int off = BLOCK / 2; off > 0; off >>= 1) {
        if (threadIdx.x < off) red[threadIdx.x] += red[threadIdx.x + off];
        __syncthreads();
    }
    if (threadIdx.x == 0) out[0] = (float)(red[0] * (double)inv_n);
}

extern "C" void kernel_launch(void* const* d_in, const int* in_sizes, int n_in,
                              void* d_out, int out_size, void* d_ws, size_t ws_size,
                              hipStream_t stream)
{
    const float* predict = (const float*)d_in[0];
    const int*   target  = (const int*)d_in[1];
    const int*   loc_b   = (const int*)d_in[2];
    const int*   loc_row = (const int*)d_in[3];
    const int*   loc_col = (const int*)d_in[4];
    float* out = (float*)d_out;

    int n = in_sizes[2];                         // N = 500000
    int nblocks = (n + BLOCK - 1) / BLOCK;       // 1954

    size_t table_bytes = (size_t)TOTAL_POS * sizeof(float);    // 16 MB
    size_t partial_bytes = (size_t)nblocks * sizeof(float);

    if (ws_size >= table_bytes + partial_bytes) {
        float* table   = (float*)d_ws;
        float* partial = (float*)((char*)d_ws + table_bytes);
        int tblocks = (TOTAL_POS + BLOCK - 1) / BLOCK;         // 16384
        nll_table_kernel<<<tblocks, BLOCK, 0, stream>>>(predict, target, table);
        table_gather_kernel<<<nblocks, BLOCK, 0, stream>>>(
            table, loc_b, loc_row, loc_col, partial, n);
        partial_loss_finalize<<<1, BLOCK, 0, stream>>>(
            partial, nblocks, out, 1.0f / (float)n);
    } else {
        float* partial = (float*)d_ws;
        partial_loss_gather<<<nblocks, BLOCK, 0, stream>>>(
            predict, target, loc_b, loc_row, loc_col, partial, n);
        partial_loss_finalize<<<1, BLOCK, 0, stream>>>(
            partial, nblocks, out, 1.0f / (float)n);
    }
}